// Round 12
// baseline (123.579 us; speedup 1.0000x reference)
//
#include <hip/hip_runtime.h>
#include <hip/hip_bf16.h>

#define NN 100000
#define NE 1600000
#define FIN 65
#define HID 128
#define NC 32
#define OUTC 65
#define NBUCK 391                     // ceil(NN / 256); bucket = dst >> 8
#define CHUNKS 400
#define CH 4000                       // edges per chunk; CHUNKS*CH == NE
#define ESTRIDE 5120                  // padded slots per bucket (mean 4096, sd 64)
#define TB 391                        // node-branch blocks (each does up to 4 tiles)
#define NTILES 1563                   // ceil(NN / 64)

typedef __attribute__((ext_vector_type(8))) short s8v;    // 8 bf16 (4 VGPRs)
typedef __attribute__((ext_vector_type(4))) float f4v;    // MFMA accumulator
#define MFMA16(a, b, c) __builtin_amdgcn_mfma_f32_16x16x32_bf16(a, b, c, 0, 0, 0)

__device__ __forceinline__ float lrelu(float v){ return v > 0.f ? v : 0.2f * v; }
// round-to-nearest-even f32 -> bf16 bits (finite inputs)
__device__ __forceinline__ short f2bs(float f){
  unsigned u = __float_as_uint(f);
  u += 0x7fffu + ((u >> 16) & 1u);
  return (short)(u >> 16);
}
__device__ __forceinline__ float bfu_lo(unsigned u){ return __uint_as_float(u << 16); }
__device__ __forceinline__ float bfu_hi(unsigned u){ return __uint_as_float(u & 0xffff0000u); }

// ---------------------------------------------------------------------------
// Kernel 0: one-time frag-order weight transpose + cursor zeroing.
// ---------------------------------------------------------------------------
__global__ __launch_bounds__(256) void k_prep(
    const float* __restrict__ Wmlp, const float* __restrict__ W1,
    const float* __restrict__ W2, short* __restrict__ wbg,
    int* __restrict__ bcursor)
{
  const int i = blockIdx.x * 256 + threadIdx.x;   // 0..8191
  if (blockIdx.x == 0)
    for (int t = threadIdx.x; t < NBUCK; t += 256) bcursor[t] = 0;
  {
    const int j = i & 7, l = (i >> 3) & 63, nt = (i >> 9) & 7, t = i >> 12;
    const int k = t * 32 + ((l >> 4) << 3) + j;
    const int col = (nt << 4) + (l & 15);
    wbg[i] = f2bs(Wmlp[k * HID + col]);
  }
  {
    const int j = i & 7, l = (i >> 3) & 63, nt = (i >> 9) & 3, t = i >> 11;
    const int k = t * 32 + ((l >> 4) << 3) + j;
    const int col = (nt << 4) + (l & 15);
    wbg[8192 + i] = f2bs(col < NC ? W1[k * NC + col] : W2[k * NC + col - NC]);
  }
}

// ---------------------------------------------------------------------------
// Kernel 1 (fused): blocks [0, TB) = MFMA front-end, 4 tiles per block with
// weights staged in LDS ONCE and reused; blocks [TB, TB+CHUNKS) = scatter.
// ---------------------------------------------------------------------------
__global__ __launch_bounds__(256) void k_main(
    const float* __restrict__ x, const short* __restrict__ wbg,
    const float* __restrict__ Wmlp, const float* __restrict__ bmlp,
    const float* __restrict__ a1s, const float* __restrict__ a1d,
    const float* __restrict__ a2s, const float* __restrict__ a2d,
    const int* __restrict__ ei,
    unsigned short* __restrict__ hb16,
    float* __restrict__ sd2, float* __restrict__ dd2,
    float* __restrict__ out,
    int* __restrict__ bcursor, int* __restrict__ ebuf)
{
  __shared__ alignas(16) short wbs[16384];     // 32 KB frag-order weights
  __shared__ alignas(16) short xbf[64 * 72];   // 9216 B
  __shared__ alignas(16) short x0b[64 * 136];  // 17408 B
  __shared__ float xc64[64];
  __shared__ float w64[128];
  __shared__ float bmv[128];
  __shared__ float avv[128];
  const int tid = threadIdx.x;

  if (blockIdx.x >= TB) {
    // ---------------- scatter branch (reuses wbs space) ----------------
    const int cb = blockIdx.x - TB;
    int* lh = (int*)wbs;             // NBUCK counts / cursors
    int* lbase = lh + NBUCK;         // NBUCK bases
    for (int i = tid; i < NBUCK; i += 256) lh[i] = 0;
    __syncthreads();
    const int4* s4 = (const int4*)ei + cb * (CH / 4);
    const int4* d4 = (const int4*)(ei + NE) + cb * (CH / 4);
    for (int i = tid; i < CH / 4; i += 256) {
      int4 v = d4[i];
      atomicAdd(&lh[v.x >> 8], 1);
      atomicAdd(&lh[v.y >> 8], 1);
      atomicAdd(&lh[v.z >> 8], 1);
      atomicAdd(&lh[v.w >> 8], 1);
    }
    __syncthreads();
    for (int i = tid; i < NBUCK; i += 256) {
      int c = lh[i];
      lbase[i] = c ? (i * ESTRIDE + atomicAdd(&bcursor[i], c)) : 0;
      lh[i] = 0;
    }
    __syncthreads();
    for (int i = tid; i < CH / 4; i += 256) {
      int4 sv = s4[i];
      int4 dv = d4[i];
      int b, r;
      b = dv.x >> 8; r = atomicAdd(&lh[b], 1); ebuf[lbase[b] + r] = (sv.x << 8) | (dv.x & 255);
      b = dv.y >> 8; r = atomicAdd(&lh[b], 1); ebuf[lbase[b] + r] = (sv.y << 8) | (dv.y & 255);
      b = dv.z >> 8; r = atomicAdd(&lh[b], 1); ebuf[lbase[b] + r] = (sv.z << 8) | (dv.z & 255);
      b = dv.w >> 8; r = atomicAdd(&lh[b], 1); ebuf[lbase[b] + r] = (sv.w << 8) | (dv.w & 255);
    }
    return;
  }

  // ---------------- node branch ----------------
  // stage weights + constants ONCE per block
  {
    const uint4* wg = (const uint4*)wbg;
    uint4* dst = (uint4*)wbs;
    #pragma unroll
    for (int i = 0; i < 8; ++i) dst[tid + i * 256] = wg[tid + i * 256];
  }
  if (tid < 128) { w64[tid] = Wmlp[64 * HID + tid]; bmv[tid] = bmlp[tid]; }
  else if (tid < 160) {
    const int q = tid - 128;
    avv[q] = a1s[q]; avv[32 + q] = a1d[q]; avv[64 + q] = a2s[q]; avv[96 + q] = a2d[q];
  }

  const int w = tid >> 6, lane = tid & 63;
  const int g = lane >> 4, q = lane & 15;
  const int rowA = w * 16 + q;
  const int rowD0 = w * 16 + g * 4;

  for (int t = 0; t < 4; ++t) {
    const int tile = blockIdx.x + t * TB;
    if (tile >= NTILES) break;
    const int base = tile * 64;

    // stage x rows for this tile
    for (int i = tid; i < 64 * 65; i += 256) {
      const int r = i / 65, c = i - r * 65;
      const int node = base + r;
      const float v = (node < NN) ? x[(size_t)node * FIN + c] : 0.f;
      if (c == 64) xc64[r] = v; else xbf[r * 72 + c] = f2bs(v);
    }
    __syncthreads();   // x (and, first iter, weights/consts) visible

    // ---- stage 1: x0 = relu(x@Wmlp + b) ----
    const s8v a0 = *(const s8v*)&xbf[rowA * 72 + g * 8];
    const s8v a1 = *(const s8v*)&xbf[rowA * 72 + 32 + g * 8];

    f4v acc[8];
    #pragma unroll
    for (int nt = 0; nt < 8; ++nt) acc[nt] = (f4v){0.f, 0.f, 0.f, 0.f};
    #pragma unroll
    for (int nt = 0; nt < 8; ++nt) {
      const s8v b0 = *(const s8v*)&wbs[(nt * 64 + lane) * 8];
      const s8v b1 = *(const s8v*)&wbs[((8 + nt) * 64 + lane) * 8];
      acc[nt] = MFMA16(a0, b0, acc[nt]);
      acc[nt] = MFMA16(a1, b1, acc[nt]);
    }

    float xc[4];
    #pragma unroll
    for (int r = 0; r < 4; ++r) xc[r] = xc64[rowD0 + r];
    float rmax[4] = {0.f, 0.f, 0.f, 0.f};
    #pragma unroll
    for (int nt = 0; nt < 8; ++nt) {
      const int col = nt * 16 + q;
      const float wvv = w64[col], bv = bmv[col];
      #pragma unroll
      for (int r = 0; r < 4; ++r) {
        const float v = fmaxf(fmaf(xc[r], wvv, acc[nt][r]) + bv, 0.f);
        rmax[r] = fmaxf(rmax[r], v);
        x0b[(rowD0 + r) * 136 + col] = f2bs(v);
      }
    }
    #pragma unroll
    for (int off = 1; off < 16; off <<= 1)
      #pragma unroll
      for (int r = 0; r < 4; ++r) rmax[r] = fmaxf(rmax[r], __shfl_xor(rmax[r], off));
    if (q == 0) {
      #pragma unroll
      for (int r = 0; r < 4; ++r) {
        const int node = base + rowD0 + r;
        if (node < NN) out[(size_t)node * OUTC + 64] = rmax[r];
      }
    }

    // ---- stage 2: h = x0 @ [W1|W2] ----  (x0b rows are wave-private)
    s8v af[4];
    #pragma unroll
    for (int t2 = 0; t2 < 4; ++t2)
      af[t2] = *(const s8v*)&x0b[rowA * 136 + t2 * 32 + g * 8];
    f4v hacc[4];
    #pragma unroll
    for (int nt = 0; nt < 4; ++nt) hacc[nt] = (f4v){0.f, 0.f, 0.f, 0.f};
    #pragma unroll
    for (int nt = 0; nt < 4; ++nt)
      #pragma unroll
      for (int t2 = 0; t2 < 4; ++t2)
        hacc[nt] = MFMA16(af[t2], *(const s8v*)&wbs[8192 + (t2 * 4 + nt) * 64 * 8 + lane * 8], hacc[nt]);

    // ---- epilogue ----
    float s1p[4], d1p[4], s2p[4], d2p[4];
    #pragma unroll
    for (int r = 0; r < 4; ++r) {
      s1p[r] = hacc[0][r] * avv[q]        + hacc[1][r] * avv[16 + q];
      d1p[r] = hacc[0][r] * avv[32 + q]   + hacc[1][r] * avv[48 + q];
      s2p[r] = hacc[2][r] * avv[64 + q]   + hacc[3][r] * avv[80 + q];
      d2p[r] = hacc[2][r] * avv[96 + q]   + hacc[3][r] * avv[112 + q];
    }
    #pragma unroll
    for (int off = 1; off < 16; off <<= 1) {
      #pragma unroll
      for (int r = 0; r < 4; ++r) {
        s1p[r] += __shfl_xor(s1p[r], off);
        d1p[r] += __shfl_xor(d1p[r], off);
        s2p[r] += __shfl_xor(s2p[r], off);
        d2p[r] += __shfl_xor(d2p[r], off);
      }
    }
    #pragma unroll
    for (int r = 0; r < 4; ++r) {
      const int node = base + rowD0 + r;
      if (node < NN) {
        #pragma unroll
        for (int nt = 0; nt < 4; ++nt)
          hb16[(size_t)node * 64 + nt * 16 + q] = (unsigned short)f2bs(hacc[nt][r]);
        if (q == 0) {
          *(float2*)&sd2[(size_t)node * 2] = make_float2(s1p[r], s2p[r]);
          *(float2*)&dd2[(size_t)node * 2] = make_float2(d1p[r], d2p[r]);
        }
      }
    }
    __syncthreads();   // all xbf reads done before next tile's staging
  }
}

// ---------------------------------------------------------------------------
// k_csr: one block per bucket. Per-dst counts -> scan -> packed rpp
// (= (absStart<<8)|deg) + compact csrc within the bucket's padded window.
// ---------------------------------------------------------------------------
__global__ __launch_bounds__(256) void k_csr(const int* __restrict__ bcursor,
                                             const int* __restrict__ ebuf,
                                             int* __restrict__ rpp,
                                             int* __restrict__ csrc)
{
  __shared__ int lh[256];
  __shared__ int wsum[4];
  const int b = blockIdx.x;
  const int e0 = b * ESTRIDE;
  const int cntb = bcursor[b];
  const int t = threadIdx.x;

  lh[t] = 0;
  __syncthreads();
  for (int i = t; i < cntb; i += 256)
    atomicAdd(&lh[ebuf[e0 + i] & 255], 1);
  __syncthreads();

  const int lane = t & 63;
  const int wid = t >> 6;
  int v = lh[t];
  const int orig = v;
  for (int off = 1; off < 64; off <<= 1) {
    int tm = __shfl_up(v, off);
    if (lane >= off) v += tm;
  }
  if (lane == 63) wsum[wid] = v;
  __syncthreads();
  int add = 0;
  for (int ww = 0; ww < wid; ++ww) add += wsum[ww];
  const int ex = v + add - orig;

  const int nb0 = b << 8;
  if (nb0 + t < NN) rpp[nb0 + t] = ((e0 + ex) << 8) | orig;
  __syncthreads();
  lh[t] = ex;
  __syncthreads();
  for (int i = t; i < cntb; i += 256) {
    int p = ebuf[e0 + i];
    int r = atomicAdd(&lh[p & 255], 1);
    csrc[e0 + r] = ((unsigned)p) >> 8;
  }
}

// ---------------------------------------------------------------------------
// k_conv v7: fused dual GAT conv + finalize. 2 nodes/wave, 32 lanes/node:
// sub = hl>>3 (4 edge-slots in flight), cg8 = hl&7 (8 channels), conv = cg8>>2.
// Per iter each lane: 1×4B csrc + 1×4B sd2 gather + 1 exp (own conv only) +
// 1×16B hb row gather + 8 fma. Denominator accumulated in-register; the
// sub-fold (xor 8,16) yields exact per-conv sums. No shuffles in the loop.
// ---------------------------------------------------------------------------
__global__ __launch_bounds__(256) void k_conv(
    const int* __restrict__ rpp, const int* __restrict__ csrc,
    const unsigned short* __restrict__ hb16,
    const float* __restrict__ sd2, const float* __restrict__ dd2,
    const float* __restrict__ x,
    const float* __restrict__ b1, const float* __restrict__ b2,
    float* __restrict__ out)
{
  const int wid = threadIdx.x >> 6;
  const int lane = threadIdx.x & 63;
  const int half = lane >> 5;
  const int hl = lane & 31;
  const int sub = hl >> 3;           // edge subslot 0..3
  const int cg8 = hl & 7;            // channels 8*cg8 .. 8*cg8+7
  const int conv = cg8 >> 2;         // 0: ch 0-31 (conv1), 1: ch 32-63 (conv2)

  const int node = blockIdx.x * 8 + wid * 2 + half;

  const int rv = rpp[node];
  const int base = ((unsigned)rv) >> 8;
  const int cnt = rv & 255;
  const float dn = dd2[(size_t)node * 2 + conv];

  const char* hbp = (const char*)hb16;
  float a[8] = {0.f, 0.f, 0.f, 0.f, 0.f, 0.f, 0.f, 0.f};
  float wsum = 0.f;

  for (int i0 = 0; i0 < cnt; i0 += 4) {
    const int idx = i0 + sub;
    const bool ok = idx < cnt;
    const int s = csrc[base + (ok ? idx : (cnt - 1))];
    const float sv = sd2[(size_t)s * 2 + conv];
    const float wgt = ok ? __expf(lrelu(sv + dn)) : 0.f;
    wsum += wgt;
    const uint4 pv = *(const uint4*)(hbp + ((size_t)s << 7) + cg8 * 16);
    a[0] = fmaf(wgt, bfu_lo(pv.x), a[0]);
    a[1] = fmaf(wgt, bfu_hi(pv.x), a[1]);
    a[2] = fmaf(wgt, bfu_lo(pv.y), a[2]);
    a[3] = fmaf(wgt, bfu_hi(pv.y), a[3]);
    a[4] = fmaf(wgt, bfu_lo(pv.z), a[4]);
    a[5] = fmaf(wgt, bfu_hi(pv.z), a[5]);
    a[6] = fmaf(wgt, bfu_lo(pv.w), a[6]);
    a[7] = fmaf(wgt, bfu_hi(pv.w), a[7]);
  }

  // fold the 4 sub stripes (bits 3,4 of lane stay within the 32-lane half)
  #pragma unroll
  for (int j = 0; j < 8; ++j) {
    a[j] += __shfl_xor(a[j], 8);
    a[j] += __shfl_xor(a[j], 16);
  }
  wsum += __shfl_xor(wsum, 8);
  wsum += __shfl_xor(wsum, 16);

  // ---- fused finalize ----
  const int ch = cg8 * 8;
  const float rden = 1.f / (wsum + 1e-16f);
  const float* bp = conv ? (b2 + ch - 32) : (b1 + ch);
  const float4 bva = *(const float4*)bp;
  const float4 bvb = *(const float4*)(bp + 4);
  float v[8];
  v[0] = a[0] * rden + bva.x; v[1] = a[1] * rden + bva.y;
  v[2] = a[2] * rden + bva.z; v[3] = a[3] * rden + bva.w;
  v[4] = a[4] * rden + bvb.x; v[5] = a[5] * rden + bvb.y;
  v[6] = a[6] * rden + bvb.z; v[7] = a[7] * rden + bvb.w;
  if (conv == 0) {
    #pragma unroll
    for (int j = 0; j < 8; ++j) v[j] = fmaxf(v[j], 0.f);
  }
  const float* xr = x + (size_t)node * OUTC;
  float* row = out + (size_t)node * OUTC;
  const float4 xa = *(const float4*)&xr[ch];
  const float4 xb = *(const float4*)&xr[ch + 4];
  v[0] += xa.x; v[1] += xa.y; v[2] += xa.z; v[3] += xa.w;
  v[4] += xb.x; v[5] += xb.y; v[6] += xb.z; v[7] += xb.w;
  const float v64 = row[64] + xr[64];          // x3 (from k_main) + residual

  float mx = v[0];
  #pragma unroll
  for (int j = 1; j < 8; ++j) mx = fmaxf(mx, v[j]);
  #pragma unroll
  for (int off = 1; off < 8; off <<= 1) mx = fmaxf(mx, __shfl_xor(mx, off));
  mx = fmaxf(mx, v64);
  float sm = 0.f;
  #pragma unroll
  for (int j = 0; j < 8; ++j) sm += __expf(v[j] - mx);
  #pragma unroll
  for (int off = 1; off < 8; off <<= 1) sm += __shfl_xor(sm, off);
  sm += __expf(v64 - mx);
  const float ls = __logf(sm) + mx;

  if (sub == 0) {
    *(float4*)&row[ch]     = make_float4(v[0] - ls, v[1] - ls, v[2] - ls, v[3] - ls);
    *(float4*)&row[ch + 4] = make_float4(v[4] - ls, v[5] - ls, v[6] - ls, v[7] - ls);
    if (hl == 0) row[64] = v64 - ls;
  }
}

// ---------------------------------------------------------------------------
extern "C" void kernel_launch(void* const* d_in, const int* in_sizes, int n_in,
                              void* d_out, int out_size, void* d_ws, size_t ws_size,
                              hipStream_t stream)
{
  const float* x    = (const float*)d_in[0];
  const int*   ei   = (const int*)d_in[1];
  const float* Wmlp = (const float*)d_in[2];
  const float* bmlp = (const float*)d_in[3];
  const float* W1   = (const float*)d_in[4];
  const float* a1s  = (const float*)d_in[5];
  const float* a1d  = (const float*)d_in[6];
  const float* b1   = (const float*)d_in[7];
  const float* W2   = (const float*)d_in[8];
  const float* a2s  = (const float*)d_in[9];
  const float* a2d  = (const float*)d_in[10];
  const float* b2   = (const float*)d_in[11];
  float* out = (float*)d_out;

  unsigned short* hb16 = (unsigned short*)d_ws;          // NN*64 bf16 (12.8 MB)
  float* sd2 = (float*)(hb16 + (size_t)NN * 64);         // 2*NN
  float* dd2 = sd2 + (size_t)2 * NN;                     // 2*NN
  int* ebuf   = (int*)(dd2 + (size_t)2 * NN);            // NBUCK*ESTRIDE (8 MB)
  int* csrc   = ebuf + (size_t)NBUCK * ESTRIDE;          // NBUCK*ESTRIDE (8 MB)
  int* rpp    = csrc + (size_t)NBUCK * ESTRIDE;          // NBUCK*256
  int* bcursor= rpp + NBUCK * 256;                       // NBUCK
  short* wbg  = (short*)(bcursor + NBUCK);               // 16384 bf16

  k_prep<<<32, 256, 0, stream>>>(Wmlp, W1, W2, wbg, bcursor);

  k_main<<<TB + CHUNKS, 256, 0, stream>>>(
      x, wbg, Wmlp, bmlp, a1s, a1d, a2s, a2d, ei,
      hb16, sd2, dd2, out, bcursor, ebuf);

  k_csr<<<NBUCK, 256, 0, stream>>>(bcursor, ebuf, rpp, csrc);

  k_conv<<<NN / 8, 256, 0, stream>>>(rpp, csrc, hb16, sd2, dd2, x, b1, b2, out);
}

// Round 13
// 117.542 us; speedup vs baseline: 1.0514x; 1.0514x over previous
//
#include <hip/hip_runtime.h>
#include <hip/hip_bf16.h>

#define NN 100000
#define NE 1600000
#define FIN 65
#define HID 128
#define NC 32
#define OUTC 65
#define NBUCK 391                     // ceil(NN / 256); bucket = dst >> 8
#define CHUNKS 800
#define CH 2000                       // edges per chunk; CHUNKS*CH == NE
#define ESTRIDE 5120                  // padded slots per bucket (mean 4096, sd 64)
#define NODE_BLOCKS 1563              // ceil(NN / 64)

typedef __attribute__((ext_vector_type(8))) short s8v;    // 8 bf16 (4 VGPRs)
typedef __attribute__((ext_vector_type(4))) float f4v;    // MFMA accumulator
#define MFMA16(a, b, c) __builtin_amdgcn_mfma_f32_16x16x32_bf16(a, b, c, 0, 0, 0)

__device__ __forceinline__ float lrelu(float v){ return v > 0.f ? v : 0.2f * v; }
// round-to-nearest-even f32 -> bf16 bits (finite inputs)
__device__ __forceinline__ short f2bs(float f){
  unsigned u = __float_as_uint(f);
  u += 0x7fffu + ((u >> 16) & 1u);
  return (short)(u >> 16);
}
__device__ __forceinline__ float bfu_lo(unsigned u){ return __uint_as_float(u << 16); }
__device__ __forceinline__ float bfu_hi(unsigned u){ return __uint_as_float(u & 0xffff0000u); }

// ---------------------------------------------------------------------------
// Kernel 0: one-time frag-order weight transpose + cursor zeroing.
// ---------------------------------------------------------------------------
__global__ __launch_bounds__(256) void k_prep(
    const float* __restrict__ Wmlp, const float* __restrict__ W1,
    const float* __restrict__ W2, short* __restrict__ wbg,
    int* __restrict__ bcursor)
{
  const int i = blockIdx.x * 256 + threadIdx.x;   // 0..8191
  if (blockIdx.x == 0)
    for (int t = threadIdx.x; t < NBUCK; t += 256) bcursor[t] = 0;
  {
    const int j = i & 7, l = (i >> 3) & 63, nt = (i >> 9) & 7, t = i >> 12;
    const int k = t * 32 + ((l >> 4) << 3) + j;
    const int col = (nt << 4) + (l & 15);
    wbg[i] = f2bs(Wmlp[k * HID + col]);
  }
  {
    const int j = i & 7, l = (i >> 3) & 63, nt = (i >> 9) & 3, t = i >> 11;
    const int k = t * 32 + ((l >> 4) << 3) + j;
    const int col = (nt << 4) + (l & 15);
    wbg[8192 + i] = f2bs(col < NC ? W1[k * NC + col] : W2[k * NC + col - NC]);
  }
}

// ---------------------------------------------------------------------------
// Kernel 1 (fused): blocks [0, NODE_BLOCKS) = MFMA front-end (weights read
// directly from L2-resident frag-order wbg — R10's best variant); blocks
// [NODE_BLOCKS, +CHUNKS) = edge bucket-scatter (now 800 smaller chunks).
// ---------------------------------------------------------------------------
__global__ __launch_bounds__(256) void k_main(
    const float* __restrict__ x, const short* __restrict__ wbg,
    const float* __restrict__ Wmlp, const float* __restrict__ bmlp,
    const float* __restrict__ a1s, const float* __restrict__ a1d,
    const float* __restrict__ a2s, const float* __restrict__ a2d,
    const int* __restrict__ ei,
    unsigned short* __restrict__ hb16,
    float* __restrict__ sd2, float* __restrict__ dd2,
    float* __restrict__ out,
    int* __restrict__ bcursor, int* __restrict__ ebuf)
{
  __shared__ alignas(16) char smem[28416];
  const int tid = threadIdx.x;

  if (blockIdx.x >= NODE_BLOCKS) {
    // ---------------- scatter branch ----------------
    const int cb = blockIdx.x - NODE_BLOCKS;
    int* lh = (int*)smem;            // NBUCK counts / cursors
    int* lbase = lh + NBUCK;         // NBUCK bases
    for (int i = tid; i < NBUCK; i += 256) lh[i] = 0;
    __syncthreads();
    const int4* s4 = (const int4*)ei + cb * (CH / 4);
    const int4* d4 = (const int4*)(ei + NE) + cb * (CH / 4);
    for (int i = tid; i < CH / 4; i += 256) {
      int4 v = d4[i];
      atomicAdd(&lh[v.x >> 8], 1);
      atomicAdd(&lh[v.y >> 8], 1);
      atomicAdd(&lh[v.z >> 8], 1);
      atomicAdd(&lh[v.w >> 8], 1);
    }
    __syncthreads();
    for (int i = tid; i < NBUCK; i += 256) {
      int c = lh[i];
      lbase[i] = c ? (i * ESTRIDE + atomicAdd(&bcursor[i], c)) : 0;
      lh[i] = 0;
    }
    __syncthreads();
    for (int i = tid; i < CH / 4; i += 256) {
      int4 sv = s4[i];
      int4 dv = d4[i];
      int b, r;
      b = dv.x >> 8; r = atomicAdd(&lh[b], 1); ebuf[lbase[b] + r] = (sv.x << 8) | (dv.x & 255);
      b = dv.y >> 8; r = atomicAdd(&lh[b], 1); ebuf[lbase[b] + r] = (sv.y << 8) | (dv.y & 255);
      b = dv.z >> 8; r = atomicAdd(&lh[b], 1); ebuf[lbase[b] + r] = (sv.z << 8) | (dv.z & 255);
      b = dv.w >> 8; r = atomicAdd(&lh[b], 1); ebuf[lbase[b] + r] = (sv.w << 8) | (dv.w & 255);
    }
    return;
  }

  // ---------------- node branch (MFMA front-end) ----------------
  short* xbf = (short*)smem;                   // 64*72 bf16   9216 B
  short* x0b = (short*)(smem + 9216);          // 64*136 bf16 17408 B
  float* xc64 = (float*)(smem + 26624);        // 64
  float* w64 = (float*)(smem + 26880);         // 128
  float* bmv = (float*)(smem + 27392);         // 128
  float* avv = (float*)(smem + 27904);         // 128

  const int base = blockIdx.x * 64;

  if (tid < 128) { w64[tid] = Wmlp[64 * HID + tid]; bmv[tid] = bmlp[tid]; }
  else if (tid < 160) {
    const int q = tid - 128;
    avv[q] = a1s[q]; avv[32 + q] = a1d[q]; avv[64 + q] = a2s[q]; avv[96 + q] = a2d[q];
  }
  if (base + 64 <= NN) {
    // fast path: flat, 16B-aligned float4 copy (tile byte base = tile*16640)
    const float4* xsrc = (const float4*)(x + (size_t)base * FIN);
    for (int i = tid; i < 1040; i += 256) {
      const float4 v = xsrc[i];
      const float vv[4] = {v.x, v.y, v.z, v.w};
      const int f0 = i * 4;
      #pragma unroll
      for (int u = 0; u < 4; ++u) {
        const int ff = f0 + u;
        const int r = (int)(((unsigned)ff * 64528u) >> 22);   // exact /65 for ff<4160
        const int c = ff - r * 65;
        if (c == 64) xc64[r] = vv[u]; else xbf[r * 72 + c] = f2bs(vv[u]);
      }
    }
  } else {
    for (int i = tid; i < 64 * 65; i += 256) {
      const int r = i / 65, c = i - r * 65;
      const int node = base + r;
      const float v = (node < NN) ? x[(size_t)node * FIN + c] : 0.f;
      if (c == 64) xc64[r] = v; else xbf[r * 72 + c] = f2bs(v);
    }
  }
  __syncthreads();

  const int w = tid >> 6, lane = tid & 63;
  const int g = lane >> 4, q = lane & 15;
  const int rowA = w * 16 + q;
  const int rowD0 = w * 16 + g * 4;
  const s8v* wv8 = (const s8v*)wbg;

  // ---- stage 1: x0 = relu(x@Wmlp + b) ----
  const s8v a0 = *(const s8v*)&xbf[rowA * 72 + g * 8];
  const s8v a1 = *(const s8v*)&xbf[rowA * 72 + 32 + g * 8];

  f4v acc[8];
  #pragma unroll
  for (int nt = 0; nt < 8; ++nt) acc[nt] = (f4v){0.f, 0.f, 0.f, 0.f};
  #pragma unroll
  for (int nt = 0; nt < 8; ++nt) {
    const s8v b0 = wv8[nt * 64 + lane];
    const s8v b1 = wv8[(8 + nt) * 64 + lane];
    acc[nt] = MFMA16(a0, b0, acc[nt]);
    acc[nt] = MFMA16(a1, b1, acc[nt]);
  }

  float xc[4];
  #pragma unroll
  for (int r = 0; r < 4; ++r) xc[r] = xc64[rowD0 + r];
  float rmax[4] = {0.f, 0.f, 0.f, 0.f};
  #pragma unroll
  for (int nt = 0; nt < 8; ++nt) {
    const int col = nt * 16 + q;
    const float wvv = w64[col], bv = bmv[col];
    #pragma unroll
    for (int r = 0; r < 4; ++r) {
      const float v = fmaxf(fmaf(xc[r], wvv, acc[nt][r]) + bv, 0.f);
      rmax[r] = fmaxf(rmax[r], v);
      x0b[(rowD0 + r) * 136 + col] = f2bs(v);
    }
  }
  #pragma unroll
  for (int off = 1; off < 16; off <<= 1)
    #pragma unroll
    for (int r = 0; r < 4; ++r) rmax[r] = fmaxf(rmax[r], __shfl_xor(rmax[r], off));
  if (q == 0) {
    #pragma unroll
    for (int r = 0; r < 4; ++r) {
      const int node = base + rowD0 + r;
      if (node < NN) out[(size_t)node * OUTC + 64] = rmax[r];
    }
  }
  // x0b rows produced and consumed by the SAME wave -> no barrier needed.

  // ---- stage 2: h = x0 @ [W1|W2] ----
  s8v af[4];
  #pragma unroll
  for (int t2 = 0; t2 < 4; ++t2)
    af[t2] = *(const s8v*)&x0b[rowA * 136 + t2 * 32 + g * 8];
  f4v hacc[4];
  #pragma unroll
  for (int nt = 0; nt < 4; ++nt) hacc[nt] = (f4v){0.f, 0.f, 0.f, 0.f};
  #pragma unroll
  for (int nt = 0; nt < 4; ++nt)
    #pragma unroll
    for (int t2 = 0; t2 < 4; ++t2)
      hacc[nt] = MFMA16(af[t2], wv8[1024 + (t2 * 4 + nt) * 64 + lane], hacc[nt]);

  // ---- epilogue ----
  float s1p[4], d1p[4], s2p[4], d2p[4];
  #pragma unroll
  for (int r = 0; r < 4; ++r) {
    s1p[r] = hacc[0][r] * avv[q]        + hacc[1][r] * avv[16 + q];
    d1p[r] = hacc[0][r] * avv[32 + q]   + hacc[1][r] * avv[48 + q];
    s2p[r] = hacc[2][r] * avv[64 + q]   + hacc[3][r] * avv[80 + q];
    d2p[r] = hacc[2][r] * avv[96 + q]   + hacc[3][r] * avv[112 + q];
  }
  #pragma unroll
  for (int off = 1; off < 16; off <<= 1) {
    #pragma unroll
    for (int r = 0; r < 4; ++r) {
      s1p[r] += __shfl_xor(s1p[r], off);
      d1p[r] += __shfl_xor(d1p[r], off);
      s2p[r] += __shfl_xor(s2p[r], off);
      d2p[r] += __shfl_xor(d2p[r], off);
    }
  }
  #pragma unroll
  for (int r = 0; r < 4; ++r) {
    const int node = base + rowD0 + r;
    if (node < NN) {
      #pragma unroll
      for (int nt = 0; nt < 4; ++nt)
        hb16[(size_t)node * 64 + nt * 16 + q] = (unsigned short)f2bs(hacc[nt][r]);
      if (q == 0) {
        *(float2*)&sd2[(size_t)node * 2] = make_float2(s1p[r], s2p[r]);
        *(float2*)&dd2[(size_t)node * 2] = make_float2(d1p[r], d2p[r]);
      }
    }
  }
}

// ---------------------------------------------------------------------------
// k_csr: one block per bucket. Per-dst counts -> scan -> packed rpp
// (= (absStart<<8)|deg) + compact csrc within the bucket's padded window.
// ---------------------------------------------------------------------------
__global__ __launch_bounds__(256) void k_csr(const int* __restrict__ bcursor,
                                             const int* __restrict__ ebuf,
                                             int* __restrict__ rpp,
                                             int* __restrict__ csrc)
{
  __shared__ int lh[256];
  __shared__ int wsum[4];
  const int b = blockIdx.x;
  const int e0 = b * ESTRIDE;
  const int cntb = bcursor[b];
  const int t = threadIdx.x;

  lh[t] = 0;
  __syncthreads();
  for (int i = t; i < cntb; i += 256)
    atomicAdd(&lh[ebuf[e0 + i] & 255], 1);
  __syncthreads();

  const int lane = t & 63;
  const int wid = t >> 6;
  int v = lh[t];
  const int orig = v;
  for (int off = 1; off < 64; off <<= 1) {
    int tm = __shfl_up(v, off);
    if (lane >= off) v += tm;
  }
  if (lane == 63) wsum[wid] = v;
  __syncthreads();
  int add = 0;
  for (int ww = 0; ww < wid; ++ww) add += wsum[ww];
  const int ex = v + add - orig;

  const int nb0 = b << 8;
  if (nb0 + t < NN) rpp[nb0 + t] = ((e0 + ex) << 8) | orig;
  __syncthreads();
  lh[t] = ex;
  __syncthreads();
  for (int i = t; i < cntb; i += 256) {
    int p = ebuf[e0 + i];
    int r = atomicAdd(&lh[p & 255], 1);
    csrc[e0 + r] = ((unsigned)p) >> 8;
  }
}

// ---------------------------------------------------------------------------
// k_conv v8 (= R8/R9's measured-best v4 + packed-weight single shfl).
// 2 nodes/wave (32 lanes each): eg = hl>>4 (edge parity), cg = hl&15
// (channels 4cg..4cg+3), conv = cg>>3. Phase A: parallel per-edge weights
// (one memory latency per 32 edges). Phase B: (s, w-packed) via 2 shfl,
// 4 independent uint2 gathers per unrolled block.
// ---------------------------------------------------------------------------
__global__ __launch_bounds__(256) void k_conv(
    const int* __restrict__ rpp, const int* __restrict__ csrc,
    const unsigned short* __restrict__ hb16,
    const float* __restrict__ sd2, const float* __restrict__ dd2,
    const float* __restrict__ x,
    const float* __restrict__ b1, const float* __restrict__ b2,
    float* __restrict__ out)
{
  const int wid = threadIdx.x >> 6;
  const int lane = threadIdx.x & 63;
  const int half = lane >> 5;
  const int hl = lane & 31;
  const int eg = hl >> 4;            // edge-slot parity
  const int cg = hl & 15;            // channel group: channels 4cg..4cg+3
  const int conv = cg >> 3;          // 0: ch 0-31 (conv1), 1: ch 32-63 (conv2)

  const int node = blockIdx.x * 8 + wid * 2 + half;

  const int rv = rpp[node];
  const int base = ((unsigned)rv) >> 8;
  const int cnt = rv & 255;
  const float2 dnv = *(const float2*)&dd2[(size_t)node * 2];

  const char* hbp = (const char*)hb16;
  float a0 = 0.f, a1 = 0.f, a2 = 0.f, a3 = 0.f;
  float den = 0.f;

  for (int chunk = 0; chunk < cnt; chunk += 32) {
    const int rem = min(cnt - chunk, 32);

    // Phase A: parallel per-edge weight computation (edge = chunk + hl)
    int sE = 0;
    float w1v = 0.f, w2v = 0.f;
    if (hl < rem) {
      sE = csrc[base + chunk + hl];
      const float2 sv = *(const float2*)&sd2[(size_t)sE * 2];
      w1v = __expf(lrelu(sv.x + dnv.x));
      w2v = __expf(lrelu(sv.y + dnv.y));
    }
    float d1 = w1v, d2 = w2v;
    #pragma unroll
    for (int off = 1; off < 32; off <<= 1) {
      d1 += __shfl_xor(d1, off);
      d2 += __shfl_xor(d2, off);
    }
    den += conv ? d2 : d1;

    // pack both conv weights as bf16 pair -> single shfl in Phase B
    const int wpk = (int)((((unsigned)(unsigned short)f2bs(w2v)) << 16) |
                           (unsigned)(unsigned short)f2bs(w1v));

    // Phase B: 8 slots (4 per eg) per unrolled block
    for (int i0 = 0; i0 < rem; i0 += 8) {
      #pragma unroll
      for (int u = 0; u < 4; ++u) {
        const int i = i0 + u * 2 + eg;          // < 32 always
        const int src = half * 32 + i;
        const int s = __shfl(sE, src);
        const unsigned wp = (unsigned)__shfl(wpk, src);
        const float w = conv ? bfu_hi(wp) : bfu_lo(wp);
        const uint2 pv = *(const uint2*)(hbp + ((size_t)s << 7) + cg * 8);
        a0 = fmaf(w, bfu_lo(pv.x), a0);
        a1 = fmaf(w, bfu_hi(pv.x), a1);
        a2 = fmaf(w, bfu_lo(pv.y), a2);
        a3 = fmaf(w, bfu_hi(pv.y), a3);
      }
    }
  }

  // fold edge parity
  a0 += __shfl_xor(a0, 16);
  a1 += __shfl_xor(a1, 16);
  a2 += __shfl_xor(a2, 16);
  a3 += __shfl_xor(a3, 16);

  // ---- fused finalize ----
  const int ch = cg * 4;
  const float rden = 1.f / (den + 1e-16f);
  float v0 = a0 * rden, v1 = a1 * rden, v2 = a2 * rden, v3 = a3 * rden;
  if (conv == 0) {
    const float4 bv = *(const float4*)&b1[ch];
    v0 = fmaxf(v0 + bv.x, 0.f);
    v1 = fmaxf(v1 + bv.y, 0.f);
    v2 = fmaxf(v2 + bv.z, 0.f);
    v3 = fmaxf(v3 + bv.w, 0.f);
  } else {
    const float4 bv = *(const float4*)&b2[ch - 32];
    v0 += bv.x; v1 += bv.y; v2 += bv.z; v3 += bv.w;
  }
  const float* xr = x + (size_t)node * OUTC;
  float* row = out + (size_t)node * OUTC;
  const float4 xr4 = *(const float4*)&xr[ch];
  v0 += xr4.x; v1 += xr4.y; v2 += xr4.z; v3 += xr4.w;
  const float v64 = row[64] + xr[64];          // x3 (from k_main) + residual

  float mx = fmaxf(fmaxf(v0, v1), fmaxf(v2, v3));
  #pragma unroll
  for (int off = 1; off < 16; off <<= 1) mx = fmaxf(mx, __shfl_xor(mx, off));
  mx = fmaxf(mx, v64);
  float sm = __expf(v0 - mx) + __expf(v1 - mx) + __expf(v2 - mx) + __expf(v3 - mx);
  #pragma unroll
  for (int off = 1; off < 16; off <<= 1) sm += __shfl_xor(sm, off);
  sm += __expf(v64 - mx);
  const float ls = __logf(sm);

  if (eg == 0) {
    *(float4*)&row[ch] = make_float4(v0 - mx - ls, v1 - mx - ls, v2 - mx - ls, v3 - mx - ls);
    if (hl == 0) row[64] = v64 - mx - ls;
  }
}

// ---------------------------------------------------------------------------
extern "C" void kernel_launch(void* const* d_in, const int* in_sizes, int n_in,
                              void* d_out, int out_size, void* d_ws, size_t ws_size,
                              hipStream_t stream)
{
  const float* x    = (const float*)d_in[0];
  const int*   ei   = (const int*)d_in[1];
  const float* Wmlp = (const float*)d_in[2];
  const float* bmlp = (const float*)d_in[3];
  const float* W1   = (const float*)d_in[4];
  const float* a1s  = (const float*)d_in[5];
  const float* a1d  = (const float*)d_in[6];
  const float* b1   = (const float*)d_in[7];
  const float* W2   = (const float*)d_in[8];
  const float* a2s  = (const float*)d_in[9];
  const float* a2d  = (const float*)d_in[10];
  const float* b2   = (const float*)d_in[11];
  float* out = (float*)d_out;

  unsigned short* hb16 = (unsigned short*)d_ws;          // NN*64 bf16 (12.8 MB)
  float* sd2 = (float*)(hb16 + (size_t)NN * 64);         // 2*NN
  float* dd2 = sd2 + (size_t)2 * NN;                     // 2*NN
  int* ebuf   = (int*)(dd2 + (size_t)2 * NN);            // NBUCK*ESTRIDE (8 MB)
  int* csrc   = ebuf + (size_t)NBUCK * ESTRIDE;          // NBUCK*ESTRIDE (8 MB)
  int* rpp    = csrc + (size_t)NBUCK * ESTRIDE;          // NBUCK*256
  int* bcursor= rpp + NBUCK * 256;                       // NBUCK
  short* wbg  = (short*)(bcursor + NBUCK);               // 16384 bf16

  k_prep<<<32, 256, 0, stream>>>(Wmlp, W1, W2, wbg, bcursor);

  k_main<<<NODE_BLOCKS + CHUNKS, 256, 0, stream>>>(
      x, wbg, Wmlp, bmlp, a1s, a1d, a2s, a2d, ei,
      hb16, sd2, dd2, out, bcursor, ebuf);

  k_csr<<<NBUCK, 256, 0, stream>>>(bcursor, ebuf, rpp, csrc);

  k_conv<<<NN / 8, 256, 0, stream>>>(rpp, csrc, hb16, sd2, dd2, x, b1, b2, out);
}

// Round 14
// 98.598 us; speedup vs baseline: 1.2534x; 1.1921x over previous
//
#include <hip/hip_runtime.h>
#include <hip/hip_bf16.h>

#define NN 100000
#define NE 1600000
#define FIN 65
#define HID 128
#define NC 32
#define OUTC 65
#define NBUCK 391                     // ceil(NN / 256); bucket = dst >> 8
#define CHUNKS 400
#define CH 4000                       // edges per chunk; CHUNKS*CH == NE
#define ESTRIDE 5120                  // padded slots per bucket (mean 4096, sd 64)
#define NODE_BLOCKS 1563              // ceil(NN / 64)

typedef __attribute__((ext_vector_type(8))) short s8v;    // 8 bf16 (4 VGPRs)
typedef __attribute__((ext_vector_type(4))) float f4v;    // MFMA accumulator
#define MFMA16(a, b, c) __builtin_amdgcn_mfma_f32_16x16x32_bf16(a, b, c, 0, 0, 0)

__device__ __forceinline__ float lrelu(float v){ return v > 0.f ? v : 0.2f * v; }
// round-to-nearest-even f32 -> bf16 bits (finite inputs)
__device__ __forceinline__ short f2bs(float f){
  unsigned u = __float_as_uint(f);
  u += 0x7fffu + ((u >> 16) & 1u);
  return (short)(u >> 16);
}
__device__ __forceinline__ float bfu_lo(unsigned u){ return __uint_as_float(u << 16); }
__device__ __forceinline__ float bfu_hi(unsigned u){ return __uint_as_float(u & 0xffff0000u); }

// ---------------------------------------------------------------------------
// Kernel 0: one-time frag-order weight transpose + cursor zeroing.
// ---------------------------------------------------------------------------
__global__ __launch_bounds__(256) void k_prep(
    const float* __restrict__ Wmlp, const float* __restrict__ W1,
    const float* __restrict__ W2, short* __restrict__ wbg,
    int* __restrict__ bcursor)
{
  const int i = blockIdx.x * 256 + threadIdx.x;   // 0..8191
  if (blockIdx.x == 0)
    for (int t = threadIdx.x; t < NBUCK; t += 256) bcursor[t] = 0;
  {
    const int j = i & 7, l = (i >> 3) & 63, nt = (i >> 9) & 7, t = i >> 12;
    const int k = t * 32 + ((l >> 4) << 3) + j;
    const int col = (nt << 4) + (l & 15);
    wbg[i] = f2bs(Wmlp[k * HID + col]);
  }
  {
    const int j = i & 7, l = (i >> 3) & 63, nt = (i >> 9) & 3, t = i >> 11;
    const int k = t * 32 + ((l >> 4) << 3) + j;
    const int col = (nt << 4) + (l & 15);
    wbg[8192 + i] = f2bs(col < NC ? W1[k * NC + col] : W2[k * NC + col - NC]);
  }
}

// ---------------------------------------------------------------------------
// Kernel 1 (fused): blocks [0, NODE_BLOCKS) = MFMA front-end with DIRECT
// per-lane A-frag loads from global x (no xbf LDS, no staging barrier);
// blocks [NODE_BLOCKS, +CHUNKS) = edge bucket-scatter. LDS 18.9 KB ->
// wave-slot-limited 8 blocks/CU (vs 5 at R10).
// ---------------------------------------------------------------------------
__global__ __launch_bounds__(256) void k_main(
    const float* __restrict__ x, const short* __restrict__ wbg,
    const float* __restrict__ Wmlp, const float* __restrict__ bmlp,
    const float* __restrict__ a1s, const float* __restrict__ a1d,
    const float* __restrict__ a2s, const float* __restrict__ a2d,
    const int* __restrict__ ei,
    unsigned short* __restrict__ hb16,
    float* __restrict__ sd2, float* __restrict__ dd2,
    float* __restrict__ out,
    int* __restrict__ bcursor, int* __restrict__ ebuf)
{
  __shared__ alignas(16) char smem[18944];
  const int tid = threadIdx.x;

  if (blockIdx.x >= NODE_BLOCKS) {
    // ---------------- scatter branch ----------------
    const int cb = blockIdx.x - NODE_BLOCKS;
    int* lh = (int*)smem;            // NBUCK counts / cursors
    int* lbase = lh + NBUCK;         // NBUCK bases
    for (int i = tid; i < NBUCK; i += 256) lh[i] = 0;
    __syncthreads();
    const int4* s4 = (const int4*)ei + cb * (CH / 4);
    const int4* d4 = (const int4*)(ei + NE) + cb * (CH / 4);
    for (int i = tid; i < CH / 4; i += 256) {
      int4 v = d4[i];
      atomicAdd(&lh[v.x >> 8], 1);
      atomicAdd(&lh[v.y >> 8], 1);
      atomicAdd(&lh[v.z >> 8], 1);
      atomicAdd(&lh[v.w >> 8], 1);
    }
    __syncthreads();
    for (int i = tid; i < NBUCK; i += 256) {
      int c = lh[i];
      lbase[i] = c ? (i * ESTRIDE + atomicAdd(&bcursor[i], c)) : 0;
      lh[i] = 0;
    }
    __syncthreads();
    for (int i = tid; i < CH / 4; i += 256) {
      int4 sv = s4[i];
      int4 dv = d4[i];
      int b, r;
      b = dv.x >> 8; r = atomicAdd(&lh[b], 1); ebuf[lbase[b] + r] = (sv.x << 8) | (dv.x & 255);
      b = dv.y >> 8; r = atomicAdd(&lh[b], 1); ebuf[lbase[b] + r] = (sv.y << 8) | (dv.y & 255);
      b = dv.z >> 8; r = atomicAdd(&lh[b], 1); ebuf[lbase[b] + r] = (sv.z << 8) | (dv.z & 255);
      b = dv.w >> 8; r = atomicAdd(&lh[b], 1); ebuf[lbase[b] + r] = (sv.w << 8) | (dv.w & 255);
    }
    return;
  }

  // ---------------- node branch (MFMA front-end) ----------------
  short* x0b = (short*)smem;                   // 64*136 bf16  17408 B
  float* w64 = (float*)(smem + 17408);         // 128
  float* bmv = (float*)(smem + 17920);         // 128
  float* avv = (float*)(smem + 18432);         // 128

  const int base = blockIdx.x * 64;
  const int w = tid >> 6, lane = tid & 63;
  const int g = lane >> 4, q = lane & 15;
  const int rowA = w * 16 + q;
  const int rowD0 = w * 16 + g * 4;
  const int nodeA = base + rowA;
  const s8v* wv8 = (const s8v*)wbg;

  // direct per-lane A-frag loads (16 independent scalar f32 loads)
  float xa[16];
  if (nodeA < NN) {
    const float* xr = x + (size_t)nodeA * FIN + g * 8;
    #pragma unroll
    for (int j = 0; j < 8; ++j) xa[j] = xr[j];
    #pragma unroll
    for (int j = 0; j < 8; ++j) xa[8 + j] = xr[32 + j];
  } else {
    #pragma unroll
    for (int j = 0; j < 16; ++j) xa[j] = 0.f;
  }
  // xc (col 64) per-lane direct loads
  float xc[4];
  #pragma unroll
  for (int r = 0; r < 4; ++r) {
    const int n2 = base + rowD0 + r;
    xc[r] = (n2 < NN) ? x[(size_t)n2 * FIN + 64] : 0.f;
  }

  // const staging (overlaps with the loads above)
  if (tid < 128) { w64[tid] = Wmlp[64 * HID + tid]; bmv[tid] = bmlp[tid]; }
  else if (tid < 160) {
    const int qq = tid - 128;
    avv[qq] = a1s[qq]; avv[32 + qq] = a1d[qq]; avv[64 + qq] = a2s[qq]; avv[96 + qq] = a2d[qq];
  }
  __syncthreads();

  s8v a0, a1;
  #pragma unroll
  for (int j = 0; j < 8; ++j) { a0[j] = f2bs(xa[j]); a1[j] = f2bs(xa[8 + j]); }

  // ---- stage 1: x0 = relu(x@Wmlp + b) ----
  f4v acc[8];
  #pragma unroll
  for (int nt = 0; nt < 8; ++nt) acc[nt] = (f4v){0.f, 0.f, 0.f, 0.f};
  #pragma unroll
  for (int nt = 0; nt < 8; ++nt) {
    const s8v b0 = wv8[nt * 64 + lane];
    const s8v b1 = wv8[(8 + nt) * 64 + lane];
    acc[nt] = MFMA16(a0, b0, acc[nt]);
    acc[nt] = MFMA16(a1, b1, acc[nt]);
  }

  float rmax[4] = {0.f, 0.f, 0.f, 0.f};
  #pragma unroll
  for (int nt = 0; nt < 8; ++nt) {
    const int col = nt * 16 + q;
    const float wvv = w64[col], bv = bmv[col];
    #pragma unroll
    for (int r = 0; r < 4; ++r) {
      const float v = fmaxf(fmaf(xc[r], wvv, acc[nt][r]) + bv, 0.f);
      rmax[r] = fmaxf(rmax[r], v);
      x0b[(rowD0 + r) * 136 + col] = f2bs(v);
    }
  }
  #pragma unroll
  for (int off = 1; off < 16; off <<= 1)
    #pragma unroll
    for (int r = 0; r < 4; ++r) rmax[r] = fmaxf(rmax[r], __shfl_xor(rmax[r], off));
  if (q == 0) {
    #pragma unroll
    for (int r = 0; r < 4; ++r) {
      const int node = base + rowD0 + r;
      if (node < NN) out[(size_t)node * OUTC + 64] = rmax[r];
    }
  }
  // x0b rows produced and consumed by the SAME wave -> no barrier needed.

  // ---- stage 2: h = x0 @ [W1|W2] ----
  s8v af[4];
  #pragma unroll
  for (int t2 = 0; t2 < 4; ++t2)
    af[t2] = *(const s8v*)&x0b[rowA * 136 + t2 * 32 + g * 8];
  f4v hacc[4];
  #pragma unroll
  for (int nt = 0; nt < 4; ++nt) hacc[nt] = (f4v){0.f, 0.f, 0.f, 0.f};
  #pragma unroll
  for (int nt = 0; nt < 4; ++nt)
    #pragma unroll
    for (int t2 = 0; t2 < 4; ++t2)
      hacc[nt] = MFMA16(af[t2], wv8[1024 + (t2 * 4 + nt) * 64 + lane], hacc[nt]);

  // ---- epilogue ----
  float s1p[4], d1p[4], s2p[4], d2p[4];
  #pragma unroll
  for (int r = 0; r < 4; ++r) {
    s1p[r] = hacc[0][r] * avv[q]        + hacc[1][r] * avv[16 + q];
    d1p[r] = hacc[0][r] * avv[32 + q]   + hacc[1][r] * avv[48 + q];
    s2p[r] = hacc[2][r] * avv[64 + q]   + hacc[3][r] * avv[80 + q];
    d2p[r] = hacc[2][r] * avv[96 + q]   + hacc[3][r] * avv[112 + q];
  }
  #pragma unroll
  for (int off = 1; off < 16; off <<= 1) {
    #pragma unroll
    for (int r = 0; r < 4; ++r) {
      s1p[r] += __shfl_xor(s1p[r], off);
      d1p[r] += __shfl_xor(d1p[r], off);
      s2p[r] += __shfl_xor(s2p[r], off);
      d2p[r] += __shfl_xor(d2p[r], off);
    }
  }
  #pragma unroll
  for (int r = 0; r < 4; ++r) {
    const int node = base + rowD0 + r;
    if (node < NN) {
      #pragma unroll
      for (int nt = 0; nt < 4; ++nt)
        hb16[(size_t)node * 64 + nt * 16 + q] = (unsigned short)f2bs(hacc[nt][r]);
      if (q == 0) {
        *(float2*)&sd2[(size_t)node * 2] = make_float2(s1p[r], s2p[r]);
        *(float2*)&dd2[(size_t)node * 2] = make_float2(d1p[r], d2p[r]);
      }
    }
  }
}

// ---------------------------------------------------------------------------
// k_csr: one block per bucket. Per-dst counts -> scan -> packed rpp
// (= (absStart<<8)|deg) + compact csrc within the bucket's padded window.
// ---------------------------------------------------------------------------
__global__ __launch_bounds__(256) void k_csr(const int* __restrict__ bcursor,
                                             const int* __restrict__ ebuf,
                                             int* __restrict__ rpp,
                                             int* __restrict__ csrc)
{
  __shared__ int lh[256];
  __shared__ int wsum[4];
  const int b = blockIdx.x;
  const int e0 = b * ESTRIDE;
  const int cntb = bcursor[b];
  const int t = threadIdx.x;

  lh[t] = 0;
  __syncthreads();
  for (int i = t; i < cntb; i += 256)
    atomicAdd(&lh[ebuf[e0 + i] & 255], 1);
  __syncthreads();

  const int lane = t & 63;
  const int wid = t >> 6;
  int v = lh[t];
  const int orig = v;
  for (int off = 1; off < 64; off <<= 1) {
    int tm = __shfl_up(v, off);
    if (lane >= off) v += tm;
  }
  if (lane == 63) wsum[wid] = v;
  __syncthreads();
  int add = 0;
  for (int ww = 0; ww < wid; ++ww) add += wsum[ww];
  const int ex = v + add - orig;

  const int nb0 = b << 8;
  if (nb0 + t < NN) rpp[nb0 + t] = ((e0 + ex) << 8) | orig;
  __syncthreads();
  lh[t] = ex;
  __syncthreads();
  for (int i = t; i < cntb; i += 256) {
    int p = ebuf[e0 + i];
    int r = atomicAdd(&lh[p & 255], 1);
    csrc[e0 + r] = ((unsigned)p) >> 8;
  }
}

// ---------------------------------------------------------------------------
// k_conv v8 (R8's measured-best v4 + packed-weight single shfl).
// 2 nodes/wave (32 lanes each): eg = hl>>4 (edge parity), cg = hl&15
// (channels 4cg..4cg+3), conv = cg>>3. Phase A: parallel per-edge weights
// (one memory latency per 32 edges). Phase B: (s, w-packed) via 2 shfl,
// 4 independent uint2 gathers per unrolled block.
// ---------------------------------------------------------------------------
__global__ __launch_bounds__(256) void k_conv(
    const int* __restrict__ rpp, const int* __restrict__ csrc,
    const unsigned short* __restrict__ hb16,
    const float* __restrict__ sd2, const float* __restrict__ dd2,
    const float* __restrict__ x,
    const float* __restrict__ b1, const float* __restrict__ b2,
    float* __restrict__ out)
{
  const int wid = threadIdx.x >> 6;
  const int lane = threadIdx.x & 63;
  const int half = lane >> 5;
  const int hl = lane & 31;
  const int eg = hl >> 4;            // edge-slot parity
  const int cg = hl & 15;            // channel group: channels 4cg..4cg+3
  const int conv = cg >> 3;          // 0: ch 0-31 (conv1), 1: ch 32-63 (conv2)

  const int node = blockIdx.x * 8 + wid * 2 + half;

  const int rv = rpp[node];
  const int base = ((unsigned)rv) >> 8;
  const int cnt = rv & 255;
  const float2 dnv = *(const float2*)&dd2[(size_t)node * 2];

  const char* hbp = (const char*)hb16;
  float a0 = 0.f, a1 = 0.f, a2 = 0.f, a3 = 0.f;
  float den = 0.f;

  for (int chunk = 0; chunk < cnt; chunk += 32) {
    const int rem = min(cnt - chunk, 32);

    // Phase A: parallel per-edge weight computation (edge = chunk + hl)
    int sE = 0;
    float w1v = 0.f, w2v = 0.f;
    if (hl < rem) {
      sE = csrc[base + chunk + hl];
      const float2 sv = *(const float2*)&sd2[(size_t)sE * 2];
      w1v = __expf(lrelu(sv.x + dnv.x));
      w2v = __expf(lrelu(sv.y + dnv.y));
    }
    float d1 = w1v, d2 = w2v;
    #pragma unroll
    for (int off = 1; off < 32; off <<= 1) {
      d1 += __shfl_xor(d1, off);
      d2 += __shfl_xor(d2, off);
    }
    den += conv ? d2 : d1;

    // pack both conv weights as bf16 pair -> single shfl in Phase B
    const int wpk = (int)((((unsigned)(unsigned short)f2bs(w2v)) << 16) |
                           (unsigned)(unsigned short)f2bs(w1v));

    // Phase B: 8 slots (4 per eg) per unrolled block
    for (int i0 = 0; i0 < rem; i0 += 8) {
      #pragma unroll
      for (int u = 0; u < 4; ++u) {
        const int i = i0 + u * 2 + eg;          // < 32 always
        const int src = half * 32 + i;
        const int s = __shfl(sE, src);
        const unsigned wp = (unsigned)__shfl(wpk, src);
        const float w = conv ? bfu_hi(wp) : bfu_lo(wp);
        const uint2 pv = *(const uint2*)(hbp + ((size_t)s << 7) + cg * 8);
        a0 = fmaf(w, bfu_lo(pv.x), a0);
        a1 = fmaf(w, bfu_hi(pv.x), a1);
        a2 = fmaf(w, bfu_lo(pv.y), a2);
        a3 = fmaf(w, bfu_hi(pv.y), a3);
      }
    }
  }

  // fold edge parity
  a0 += __shfl_xor(a0, 16);
  a1 += __shfl_xor(a1, 16);
  a2 += __shfl_xor(a2, 16);
  a3 += __shfl_xor(a3, 16);

  // ---- fused finalize ----
  const int ch = cg * 4;
  const float rden = 1.f / (den + 1e-16f);
  float v0 = a0 * rden, v1 = a1 * rden, v2 = a2 * rden, v3 = a3 * rden;
  if (conv == 0) {
    const float4 bv = *(const float4*)&b1[ch];
    v0 = fmaxf(v0 + bv.x, 0.f);
    v1 = fmaxf(v1 + bv.y, 0.f);
    v2 = fmaxf(v2 + bv.z, 0.f);
    v3 = fmaxf(v3 + bv.w, 0.f);
  } else {
    const float4 bv = *(const float4*)&b2[ch - 32];
    v0 += bv.x; v1 += bv.y; v2 += bv.z; v3 += bv.w;
  }
  const float* xr = x + (size_t)node * OUTC;
  float* row = out + (size_t)node * OUTC;
  const float4 xr4 = *(const float4*)&xr[ch];
  v0 += xr4.x; v1 += xr4.y; v2 += xr4.z; v3 += xr4.w;
  const float v64 = row[64] + xr[64];          // x3 (from k_main) + residual

  float mx = fmaxf(fmaxf(v0, v1), fmaxf(v2, v3));
  #pragma unroll
  for (int off = 1; off < 16; off <<= 1) mx = fmaxf(mx, __shfl_xor(mx, off));
  mx = fmaxf(mx, v64);
  float sm = __expf(v0 - mx) + __expf(v1 - mx) + __expf(v2 - mx) + __expf(v3 - mx);
  #pragma unroll
  for (int off = 1; off < 16; off <<= 1) sm += __shfl_xor(sm, off);
  sm += __expf(v64 - mx);
  const float ls = __logf(sm);

  if (eg == 0) {
    *(float4*)&row[ch] = make_float4(v0 - mx - ls, v1 - mx - ls, v2 - mx - ls, v3 - mx - ls);
    if (hl == 0) row[64] = v64 - mx - ls;
  }
}

// ---------------------------------------------------------------------------
extern "C" void kernel_launch(void* const* d_in, const int* in_sizes, int n_in,
                              void* d_out, int out_size, void* d_ws, size_t ws_size,
                              hipStream_t stream)
{
  const float* x    = (const float*)d_in[0];
  const int*   ei   = (const int*)d_in[1];
  const float* Wmlp = (const float*)d_in[2];
  const float* bmlp = (const float*)d_in[3];
  const float* W1   = (const float*)d_in[4];
  const float* a1s  = (const float*)d_in[5];
  const float* a1d  = (const float*)d_in[6];
  const float* b1   = (const float*)d_in[7];
  const float* W2   = (const float*)d_in[8];
  const float* a2s  = (const float*)d_in[9];
  const float* a2d  = (const float*)d_in[10];
  const float* b2   = (const float*)d_in[11];
  float* out = (float*)d_out;

  unsigned short* hb16 = (unsigned short*)d_ws;          // NN*64 bf16 (12.8 MB)
  float* sd2 = (float*)(hb16 + (size_t)NN * 64);         // 2*NN
  float* dd2 = sd2 + (size_t)2 * NN;                     // 2*NN
  int* ebuf   = (int*)(dd2 + (size_t)2 * NN);            // NBUCK*ESTRIDE (8 MB)
  int* csrc   = ebuf + (size_t)NBUCK * ESTRIDE;          // NBUCK*ESTRIDE (8 MB)
  int* rpp    = csrc + (size_t)NBUCK * ESTRIDE;          // NBUCK*256
  int* bcursor= rpp + NBUCK * 256;                       // NBUCK
  short* wbg  = (short*)(bcursor + NBUCK);               // 16384 bf16

  k_prep<<<32, 256, 0, stream>>>(Wmlp, W1, W2, wbg, bcursor);

  k_main<<<NODE_BLOCKS + CHUNKS, 256, 0, stream>>>(
      x, wbg, Wmlp, bmlp, a1s, a1d, a2s, a2d, ei,
      hb16, sd2, dd2, out, bcursor, ebuf);

  k_csr<<<NBUCK, 256, 0, stream>>>(bcursor, ebuf, rpp, csrc);

  k_conv<<<NN / 8, 256, 0, stream>>>(rpp, csrc, hb16, sd2, dd2, x, b1, b2, out);
}

// Round 15
// 95.677 us; speedup vs baseline: 1.2916x; 1.0305x over previous
//
#include <hip/hip_runtime.h>
#include <hip/hip_bf16.h>

#define NN 100000
#define NE 1600000
#define FIN 65
#define HID 128
#define NC 32
#define OUTC 65
#define NBUCK 391                     // ceil(NN / 256); bucket = dst >> 8
#define CHUNKS 400
#define CH 4000                       // edges per chunk; CHUNKS*CH == NE
#define ESTRIDE 5120                  // padded slots per bucket (mean 4096, sd 64)
#define NODE_BLOCKS 1563              // ceil(NN / 64)

typedef __attribute__((ext_vector_type(8))) short s8v;    // 8 bf16 (4 VGPRs)
typedef __attribute__((ext_vector_type(4))) float f4v;    // MFMA accumulator
typedef __attribute__((ext_vector_type(2))) float f2v;
#define MFMA16(a, b, c) __builtin_amdgcn_mfma_f32_16x16x32_bf16(a, b, c, 0, 0, 0)

__device__ __forceinline__ float lrelu(float v){ return v > 0.f ? v : 0.2f * v; }
// round-to-nearest-even f32 -> bf16 bits (finite inputs)
__device__ __forceinline__ short f2bs(float f){
  unsigned u = __float_as_uint(f);
  u += 0x7fffu + ((u >> 16) & 1u);
  return (short)(u >> 16);
}
__device__ __forceinline__ float bfu_lo(unsigned u){ return __uint_as_float(u << 16); }
__device__ __forceinline__ float bfu_hi(unsigned u){ return __uint_as_float(u & 0xffff0000u); }
// f32 -> OCP fp8 e4m3 (HW convert, RNE)
__device__ __forceinline__ unsigned char f2fp8(float f){
  int p = __builtin_amdgcn_cvt_pk_fp8_f32(f, f, 0, false);
  return (unsigned char)(p & 0xff);
}

// ---------------------------------------------------------------------------
// Kernel 0: one-time frag-order weight transpose + cursor zeroing.
// ---------------------------------------------------------------------------
__global__ __launch_bounds__(256) void k_prep(
    const float* __restrict__ Wmlp, const float* __restrict__ W1,
    const float* __restrict__ W2, short* __restrict__ wbg,
    int* __restrict__ bcursor)
{
  const int i = blockIdx.x * 256 + threadIdx.x;   // 0..8191
  if (blockIdx.x == 0)
    for (int t = threadIdx.x; t < NBUCK; t += 256) bcursor[t] = 0;
  {
    const int j = i & 7, l = (i >> 3) & 63, nt = (i >> 9) & 7, t = i >> 12;
    const int k = t * 32 + ((l >> 4) << 3) + j;
    const int col = (nt << 4) + (l & 15);
    wbg[i] = f2bs(Wmlp[k * HID + col]);
  }
  {
    const int j = i & 7, l = (i >> 3) & 63, nt = (i >> 9) & 3, t = i >> 11;
    const int k = t * 32 + ((l >> 4) << 3) + j;
    const int col = (nt << 4) + (l & 15);
    wbg[8192 + i] = f2bs(col < NC ? W1[k * NC + col] : W2[k * NC + col - NC]);
  }
}

// ---------------------------------------------------------------------------
// Kernel 1 (fused): blocks [0, NODE_BLOCKS) = MFMA front-end with direct
// per-lane A-frag loads (R14); blocks [NODE_BLOCKS, +CHUNKS) = scatter.
// h output now stored as fp8 e4m3 (64 B/row).
// ---------------------------------------------------------------------------
__global__ __launch_bounds__(256) void k_main(
    const float* __restrict__ x, const short* __restrict__ wbg,
    const float* __restrict__ Wmlp, const float* __restrict__ bmlp,
    const float* __restrict__ a1s, const float* __restrict__ a1d,
    const float* __restrict__ a2s, const float* __restrict__ a2d,
    const int* __restrict__ ei,
    unsigned char* __restrict__ hb8,
    float* __restrict__ sd2, float* __restrict__ dd2,
    float* __restrict__ out,
    int* __restrict__ bcursor, int* __restrict__ ebuf)
{
  __shared__ alignas(16) char smem[18944];
  const int tid = threadIdx.x;

  if (blockIdx.x >= NODE_BLOCKS) {
    // ---------------- scatter branch ----------------
    const int cb = blockIdx.x - NODE_BLOCKS;
    int* lh = (int*)smem;            // NBUCK counts / cursors
    int* lbase = lh + NBUCK;         // NBUCK bases
    for (int i = tid; i < NBUCK; i += 256) lh[i] = 0;
    __syncthreads();
    const int4* s4 = (const int4*)ei + cb * (CH / 4);
    const int4* d4 = (const int4*)(ei + NE) + cb * (CH / 4);
    for (int i = tid; i < CH / 4; i += 256) {
      int4 v = d4[i];
      atomicAdd(&lh[v.x >> 8], 1);
      atomicAdd(&lh[v.y >> 8], 1);
      atomicAdd(&lh[v.z >> 8], 1);
      atomicAdd(&lh[v.w >> 8], 1);
    }
    __syncthreads();
    for (int i = tid; i < NBUCK; i += 256) {
      int c = lh[i];
      lbase[i] = c ? (i * ESTRIDE + atomicAdd(&bcursor[i], c)) : 0;
      lh[i] = 0;
    }
    __syncthreads();
    for (int i = tid; i < CH / 4; i += 256) {
      int4 sv = s4[i];
      int4 dv = d4[i];
      int b, r;
      b = dv.x >> 8; r = atomicAdd(&lh[b], 1); ebuf[lbase[b] + r] = (sv.x << 8) | (dv.x & 255);
      b = dv.y >> 8; r = atomicAdd(&lh[b], 1); ebuf[lbase[b] + r] = (sv.y << 8) | (dv.y & 255);
      b = dv.z >> 8; r = atomicAdd(&lh[b], 1); ebuf[lbase[b] + r] = (sv.z << 8) | (dv.z & 255);
      b = dv.w >> 8; r = atomicAdd(&lh[b], 1); ebuf[lbase[b] + r] = (sv.w << 8) | (dv.w & 255);
    }
    return;
  }

  // ---------------- node branch (MFMA front-end) ----------------
  short* x0b = (short*)smem;                   // 64*136 bf16  17408 B
  float* w64 = (float*)(smem + 17408);         // 128
  float* bmv = (float*)(smem + 17920);         // 128
  float* avv = (float*)(smem + 18432);         // 128

  const int base = blockIdx.x * 64;
  const int w = tid >> 6, lane = tid & 63;
  const int g = lane >> 4, q = lane & 15;
  const int rowA = w * 16 + q;
  const int rowD0 = w * 16 + g * 4;
  const int nodeA = base + rowA;
  const s8v* wv8 = (const s8v*)wbg;

  // direct per-lane A-frag loads (16 independent scalar f32 loads)
  float xa[16];
  if (nodeA < NN) {
    const float* xr = x + (size_t)nodeA * FIN + g * 8;
    #pragma unroll
    for (int j = 0; j < 8; ++j) xa[j] = xr[j];
    #pragma unroll
    for (int j = 0; j < 8; ++j) xa[8 + j] = xr[32 + j];
  } else {
    #pragma unroll
    for (int j = 0; j < 16; ++j) xa[j] = 0.f;
  }
  // xc (col 64) per-lane direct loads
  float xc[4];
  #pragma unroll
  for (int r = 0; r < 4; ++r) {
    const int n2 = base + rowD0 + r;
    xc[r] = (n2 < NN) ? x[(size_t)n2 * FIN + 64] : 0.f;
  }

  // const staging (overlaps with the loads above)
  if (tid < 128) { w64[tid] = Wmlp[64 * HID + tid]; bmv[tid] = bmlp[tid]; }
  else if (tid < 160) {
    const int qq = tid - 128;
    avv[qq] = a1s[qq]; avv[32 + qq] = a1d[qq]; avv[64 + qq] = a2s[qq]; avv[96 + qq] = a2d[qq];
  }
  __syncthreads();

  s8v a0, a1;
  #pragma unroll
  for (int j = 0; j < 8; ++j) { a0[j] = f2bs(xa[j]); a1[j] = f2bs(xa[8 + j]); }

  // ---- stage 1: x0 = relu(x@Wmlp + b) ----
  f4v acc[8];
  #pragma unroll
  for (int nt = 0; nt < 8; ++nt) acc[nt] = (f4v){0.f, 0.f, 0.f, 0.f};
  #pragma unroll
  for (int nt = 0; nt < 8; ++nt) {
    const s8v b0 = wv8[nt * 64 + lane];
    const s8v b1 = wv8[(8 + nt) * 64 + lane];
    acc[nt] = MFMA16(a0, b0, acc[nt]);
    acc[nt] = MFMA16(a1, b1, acc[nt]);
  }

  float rmax[4] = {0.f, 0.f, 0.f, 0.f};
  #pragma unroll
  for (int nt = 0; nt < 8; ++nt) {
    const int col = nt * 16 + q;
    const float wvv = w64[col], bv = bmv[col];
    #pragma unroll
    for (int r = 0; r < 4; ++r) {
      const float v = fmaxf(fmaf(xc[r], wvv, acc[nt][r]) + bv, 0.f);
      rmax[r] = fmaxf(rmax[r], v);
      x0b[(rowD0 + r) * 136 + col] = f2bs(v);
    }
  }
  #pragma unroll
  for (int off = 1; off < 16; off <<= 1)
    #pragma unroll
    for (int r = 0; r < 4; ++r) rmax[r] = fmaxf(rmax[r], __shfl_xor(rmax[r], off));
  if (q == 0) {
    #pragma unroll
    for (int r = 0; r < 4; ++r) {
      const int node = base + rowD0 + r;
      if (node < NN) out[(size_t)node * OUTC + 64] = rmax[r];
    }
  }
  // x0b rows produced and consumed by the SAME wave -> no barrier needed.

  // ---- stage 2: h = x0 @ [W1|W2] ----
  s8v af[4];
  #pragma unroll
  for (int t2 = 0; t2 < 4; ++t2)
    af[t2] = *(const s8v*)&x0b[rowA * 136 + t2 * 32 + g * 8];
  f4v hacc[4];
  #pragma unroll
  for (int nt = 0; nt < 4; ++nt) hacc[nt] = (f4v){0.f, 0.f, 0.f, 0.f};
  #pragma unroll
  for (int nt = 0; nt < 4; ++nt)
    #pragma unroll
    for (int t2 = 0; t2 < 4; ++t2)
      hacc[nt] = MFMA16(af[t2], wv8[1024 + (t2 * 4 + nt) * 64 + lane], hacc[nt]);

  // ---- epilogue ----
  float s1p[4], d1p[4], s2p[4], d2p[4];
  #pragma unroll
  for (int r = 0; r < 4; ++r) {
    s1p[r] = hacc[0][r] * avv[q]        + hacc[1][r] * avv[16 + q];
    d1p[r] = hacc[0][r] * avv[32 + q]   + hacc[1][r] * avv[48 + q];
    s2p[r] = hacc[2][r] * avv[64 + q]   + hacc[3][r] * avv[80 + q];
    d2p[r] = hacc[2][r] * avv[96 + q]   + hacc[3][r] * avv[112 + q];
  }
  #pragma unroll
  for (int off = 1; off < 16; off <<= 1) {
    #pragma unroll
    for (int r = 0; r < 4; ++r) {
      s1p[r] += __shfl_xor(s1p[r], off);
      d1p[r] += __shfl_xor(d1p[r], off);
      s2p[r] += __shfl_xor(s2p[r], off);
      d2p[r] += __shfl_xor(d2p[r], off);
    }
  }
  #pragma unroll
  for (int r = 0; r < 4; ++r) {
    const int node = base + rowD0 + r;
    if (node < NN) {
      #pragma unroll
      for (int nt = 0; nt < 4; ++nt)
        hb8[(size_t)node * 64 + nt * 16 + q] = f2fp8(hacc[nt][r]);
      if (q == 0) {
        *(float2*)&sd2[(size_t)node * 2] = make_float2(s1p[r], s2p[r]);
        *(float2*)&dd2[(size_t)node * 2] = make_float2(d1p[r], d2p[r]);
      }
    }
  }
}

// ---------------------------------------------------------------------------
// k_csr: one block per bucket. Per-dst counts -> scan -> packed rpp
// (= (absStart<<8)|deg) + compact csrc within the bucket's padded window.
// ---------------------------------------------------------------------------
__global__ __launch_bounds__(256) void k_csr(const int* __restrict__ bcursor,
                                             const int* __restrict__ ebuf,
                                             int* __restrict__ rpp,
                                             int* __restrict__ csrc)
{
  __shared__ int lh[256];
  __shared__ int wsum[4];
  const int b = blockIdx.x;
  const int e0 = b * ESTRIDE;
  const int cntb = bcursor[b];
  const int t = threadIdx.x;

  lh[t] = 0;
  __syncthreads();
  for (int i = t; i < cntb; i += 256)
    atomicAdd(&lh[ebuf[e0 + i] & 255], 1);
  __syncthreads();

  const int lane = t & 63;
  const int wid = t >> 6;
  int v = lh[t];
  const int orig = v;
  for (int off = 1; off < 64; off <<= 1) {
    int tm = __shfl_up(v, off);
    if (lane >= off) v += tm;
  }
  if (lane == 63) wsum[wid] = v;
  __syncthreads();
  int add = 0;
  for (int ww = 0; ww < wid; ++ww) add += wsum[ww];
  const int ex = v + add - orig;

  const int nb0 = b << 8;
  if (nb0 + t < NN) rpp[nb0 + t] = ((e0 + ex) << 8) | orig;
  __syncthreads();
  lh[t] = ex;
  __syncthreads();
  for (int i = t; i < cntb; i += 256) {
    int p = ebuf[e0 + i];
    int r = atomicAdd(&lh[p & 255], 1);
    csrc[e0 + r] = ((unsigned)p) >> 8;
  }
}

// ---------------------------------------------------------------------------
// k_conv v9 (= v8 structure, fp8 hb rows: 64 B gather, HW cvt unpack).
// 2 nodes/wave (32 lanes each): eg = hl>>4 (edge parity), cg = hl&15
// (channels 4cg..4cg+3), conv = cg>>3. Phase A: parallel per-edge weights.
// Phase B: (s, w-packed) via 2 shfl, 4 independent dword gathers per block;
// v_cvt_pk_f32_fp8 unpack (2 instr per 4 channels).
// ---------------------------------------------------------------------------
__global__ __launch_bounds__(256) void k_conv(
    const int* __restrict__ rpp, const int* __restrict__ csrc,
    const unsigned char* __restrict__ hb8,
    const float* __restrict__ sd2, const float* __restrict__ dd2,
    const float* __restrict__ x,
    const float* __restrict__ b1, const float* __restrict__ b2,
    float* __restrict__ out)
{
  const int wid = threadIdx.x >> 6;
  const int lane = threadIdx.x & 63;
  const int half = lane >> 5;
  const int hl = lane & 31;
  const int eg = hl >> 4;            // edge-slot parity
  const int cg = hl & 15;            // channel group: channels 4cg..4cg+3
  const int conv = cg >> 3;          // 0: ch 0-31 (conv1), 1: ch 32-63 (conv2)

  const int node = blockIdx.x * 8 + wid * 2 + half;

  const int rv = rpp[node];
  const int base = ((unsigned)rv) >> 8;
  const int cnt = rv & 255;
  const float2 dnv = *(const float2*)&dd2[(size_t)node * 2];

  float a0 = 0.f, a1 = 0.f, a2 = 0.f, a3 = 0.f;
  float den = 0.f;

  for (int chunk = 0; chunk < cnt; chunk += 32) {
    const int rem = min(cnt - chunk, 32);

    // Phase A: parallel per-edge weight computation (edge = chunk + hl)
    int sE = 0;
    float w1v = 0.f, w2v = 0.f;
    if (hl < rem) {
      sE = csrc[base + chunk + hl];
      const float2 sv = *(const float2*)&sd2[(size_t)sE * 2];
      w1v = __expf(lrelu(sv.x + dnv.x));
      w2v = __expf(lrelu(sv.y + dnv.y));
    }
    float d1 = w1v, d2 = w2v;
    #pragma unroll
    for (int off = 1; off < 32; off <<= 1) {
      d1 += __shfl_xor(d1, off);
      d2 += __shfl_xor(d2, off);
    }
    den += conv ? d2 : d1;

    // pack both conv weights as bf16 pair -> single shfl in Phase B
    const int wpk = (int)((((unsigned)(unsigned short)f2bs(w2v)) << 16) |
                           (unsigned)(unsigned short)f2bs(w1v));

    // Phase B: 8 slots (4 per eg) per unrolled block; 4B fp8 gathers
    for (int i0 = 0; i0 < rem; i0 += 8) {
      #pragma unroll
      for (int u = 0; u < 4; ++u) {
        const int i = i0 + u * 2 + eg;          // < 32 always
        const int src = half * 32 + i;
        const int s = __shfl(sE, src);
        const unsigned wp = (unsigned)__shfl(wpk, src);
        const float w = conv ? bfu_hi(wp) : bfu_lo(wp);
        const unsigned pv = *(const unsigned*)(hb8 + ((size_t)s << 6) + cg * 4);
        const f2v lo = __builtin_amdgcn_cvt_pk_f32_fp8((int)pv, false);
        const f2v hi = __builtin_amdgcn_cvt_pk_f32_fp8((int)pv, true);
        a0 = fmaf(w, lo[0], a0);
        a1 = fmaf(w, lo[1], a1);
        a2 = fmaf(w, hi[0], a2);
        a3 = fmaf(w, hi[1], a3);
      }
    }
  }

  // fold edge parity
  a0 += __shfl_xor(a0, 16);
  a1 += __shfl_xor(a1, 16);
  a2 += __shfl_xor(a2, 16);
  a3 += __shfl_xor(a3, 16);

  // ---- fused finalize ----
  const int ch = cg * 4;
  const float rden = 1.f / (den + 1e-16f);
  float v0 = a0 * rden, v1 = a1 * rden, v2 = a2 * rden, v3 = a3 * rden;
  if (conv == 0) {
    const float4 bv = *(const float4*)&b1[ch];
    v0 = fmaxf(v0 + bv.x, 0.f);
    v1 = fmaxf(v1 + bv.y, 0.f);
    v2 = fmaxf(v2 + bv.z, 0.f);
    v3 = fmaxf(v3 + bv.w, 0.f);
  } else {
    const float4 bv = *(const float4*)&b2[ch - 32];
    v0 += bv.x; v1 += bv.y; v2 += bv.z; v3 += bv.w;
  }
  const float* xr = x + (size_t)node * OUTC;
  float* row = out + (size_t)node * OUTC;
  const float4 xr4 = *(const float4*)&xr[ch];
  v0 += xr4.x; v1 += xr4.y; v2 += xr4.z; v3 += xr4.w;
  const float v64 = row[64] + xr[64];          // x3 (from k_main) + residual

  float mx = fmaxf(fmaxf(v0, v1), fmaxf(v2, v3));
  #pragma unroll
  for (int off = 1; off < 16; off <<= 1) mx = fmaxf(mx, __shfl_xor(mx, off));
  mx = fmaxf(mx, v64);
  float sm = __expf(v0 - mx) + __expf(v1 - mx) + __expf(v2 - mx) + __expf(v3 - mx);
  #pragma unroll
  for (int off = 1; off < 16; off <<= 1) sm += __shfl_xor(sm, off);
  sm += __expf(v64 - mx);
  const float ls = __logf(sm);

  if (eg == 0) {
    *(float4*)&row[ch] = make_float4(v0 - mx - ls, v1 - mx - ls, v2 - mx - ls, v3 - mx - ls);
    if (hl == 0) row[64] = v64 - mx - ls;
  }
}

// ---------------------------------------------------------------------------
extern "C" void kernel_launch(void* const* d_in, const int* in_sizes, int n_in,
                              void* d_out, int out_size, void* d_ws, size_t ws_size,
                              hipStream_t stream)
{
  const float* x    = (const float*)d_in[0];
  const int*   ei   = (const int*)d_in[1];
  const float* Wmlp = (const float*)d_in[2];
  const float* bmlp = (const float*)d_in[3];
  const float* W1   = (const float*)d_in[4];
  const float* a1s  = (const float*)d_in[5];
  const float* a1d  = (const float*)d_in[6];
  const float* b1   = (const float*)d_in[7];
  const float* W2   = (const float*)d_in[8];
  const float* a2s  = (const float*)d_in[9];
  const float* a2d  = (const float*)d_in[10];
  const float* b2   = (const float*)d_in[11];
  float* out = (float*)d_out;

  unsigned char* hb8 = (unsigned char*)d_ws;             // NN*64 fp8 (6.4 MB)
  float* sd2 = (float*)(hb8 + (size_t)NN * 64);          // 2*NN
  float* dd2 = sd2 + (size_t)2 * NN;                     // 2*NN
  int* ebuf   = (int*)(dd2 + (size_t)2 * NN);            // NBUCK*ESTRIDE (8 MB)
  int* csrc   = ebuf + (size_t)NBUCK * ESTRIDE;          // NBUCK*ESTRIDE (8 MB)
  int* rpp    = csrc + (size_t)NBUCK * ESTRIDE;          // NBUCK*256
  int* bcursor= rpp + NBUCK * 256;                       // NBUCK
  short* wbg  = (short*)(bcursor + NBUCK);               // 16384 bf16

  k_prep<<<32, 256, 0, stream>>>(Wmlp, W1, W2, wbg, bcursor);

  k_main<<<NODE_BLOCKS + CHUNKS, 256, 0, stream>>>(
      x, wbg, Wmlp, bmlp, a1s, a1d, a2s, a2d, ei,
      hb8, sd2, dd2, out, bcursor, ebuf);

  k_csr<<<NBUCK, 256, 0, stream>>>(bcursor, ebuf, rpp, csrc);

  k_conv<<<NN / 8, 256, 0, stream>>>(rpp, csrc, hb8, sd2, dd2, x, b1, b2, out);
}